// Round 4
// baseline (375.739 us; speedup 1.0000x reference)
//
#include <hip/hip_runtime.h>

#define B_  16
#define S_  1024
#define D_  384
#define QK_ 64

typedef __attribute__((ext_vector_type(8))) short bf16x8;
typedef __attribute__((ext_vector_type(4))) short bf16x4;
typedef __attribute__((ext_vector_type(4))) float f32x4;

__device__ __forceinline__ short f2bf(float f) {
  union { float f; unsigned u; } v; v.f = f;
  unsigned r = v.u + 0x7FFFu + ((v.u >> 16) & 1u);   // round-to-nearest-even
  return (short)(r >> 16);
}

__device__ __forceinline__ bf16x4 cvt4(const float4 v) {
  bf16x4 r;
  r[0] = f2bf(v.x); r[1] = f2bf(v.y); r[2] = f2bf(v.z); r[3] = f2bf(v.w);
  return r;
}

__device__ __forceinline__ bf16x4 cvt4v(const f32x4 v) {
  bf16x4 r;
  r[0] = f2bf(v[0]); r[1] = f2bf(v[1]); r[2] = f2bf(v[2]); r[3] = f2bf(v[3]);
  return r;
}

// ---------------------------------------------------------------------------
// K1 v4: per-position projection, (pos, half) blocks. The weight slab
// (64 rows x 384 ch = 96 KB) is read in STRICTLY ASCENDING order, 1 KB per
// wave-instruction (li = tid + 256r) -- the same address stream the 6.3 TB/s
// copy ubench uses -- with non-temporal loads (weights have zero reuse).
// Staged to UNPADDED ws[64][384] bf16 with XOR swizzle (idx ^= (row&7)<<3):
// linear writes stay conflict-free, and the b128 fragment reads spread
// across all 32 banks (structural minimum). x staged once in xs.
// ---------------------------------------------------------------------------
__global__ __launch_bounds__(256) void k_proj(
    const float* __restrict__ x, const float* __restrict__ qw,
    const float* __restrict__ qb, const float* __restrict__ kw,
    unsigned short* __restrict__ Qb, unsigned short* __restrict__ Kb) {
  __shared__ __attribute__((aligned(16))) short xs[16 * 392];   // 12.5 KB
  __shared__ __attribute__((aligned(16))) short ws[64 * 384];   // 48 KB

  const int pos  = blockIdx.x >> 1;
  const int half = blockIdx.x & 1;
  const int tid  = threadIdx.x;
  const int lane = tid & 63;
  const int w    = tid >> 6;
  const int col  = lane & 15;
  const int quad = lane >> 4;

  // x staging loads first (oldest in the vmem queue)
  float4 xv[6];
#pragma unroll
  for (int r = 0; r < 6; ++r) {
    int li = tid + 256 * r;
    int brow = li / 96, c4 = li % 96;
    xv[r] = *(const float4*)&x[(brow * S_ + pos) * D_ + 4 * c4];
  }

  const float* wsrc  = half ? kw : qw;
  const float* wbase = wsrc + (size_t)pos * 64 * D_;   // this block's 96 KB slab

  // linear slab read: 24 x (64 lanes x 16 B contiguous), non-temporal
  f32x4 wv[24];
#pragma unroll
  for (int r = 0; r < 24; ++r) {
    const int li = tid + 256 * r;
    wv[r] = __builtin_nontemporal_load((const f32x4*)(wbase + 4 * (size_t)li));
  }

  // stage x (waits only the 6 oldest loads)
#pragma unroll
  for (int r = 0; r < 6; ++r) {
    int li = tid + 256 * r;
    int brow = li / 96, c4 = li % 96;
    *(bf16x4*)&xs[brow * 392 + 4 * c4] = cvt4(xv[r]);
  }
  // stage weights: linear dest + XOR swizzle on short-index bits 3..5
#pragma unroll
  for (int r = 0; r < 24; ++r) {
    const int li  = tid + 256 * r;
    const int row = li / 96, c4 = li % 96;
    const int idx = (row * 384 + 4 * c4) ^ ((row & 7) << 3);
    *(bf16x4*)&ws[idx] = cvt4v(wv[r]);
  }
  __syncthreads();

  const int jrow = w * 16 + col;                       // B-fragment row (j)
  const int xor3 = (jrow & 7) << 3;
  f32x4 acc = {0.f, 0.f, 0.f, 0.f};
#pragma unroll
  for (int ks = 0; ks < 12; ++ks) {
    bf16x8 aF = *(const bf16x8*)&xs[col * 392 + ks * 32 + quad * 8];
    bf16x8 bF = *(const bf16x8*)&ws[(jrow * 384 + ks * 32 + quad * 8) ^ xor3];
    acc = __builtin_amdgcn_mfma_f32_16x16x32_bf16(aF, bF, acc, 0, 0, 0);
  }

  const float SCALE = 0.051031036307982884f;   // 384^-0.5
#pragma unroll
  for (int r = 0; r < 4; ++r) {
    const int brow = quad * 4 + r;             // C/D: row = quad*4 + reg
    float v = acc[r];
    if (half == 0) {
      v = SCALE * (v + qb[pos * QK_ + jrow]);
      Qb[(brow * S_ + pos) * QK_ + jrow] = (unsigned short)f2bf(v);
    } else {
      Kb[(brow * S_ + pos) * QK_ + jrow] = (unsigned short)f2bf(v);
    }
  }
}

// ---------------------------------------------------------------------------
// K-XT: one-time transpose x[b][j][c] fp32 -> Xt[b][c][j] bf16. Classic
// 32x32 tile via padded LDS (stride 33 floats -> conflict-free both sides).
// ---------------------------------------------------------------------------
__global__ __launch_bounds__(256) void k_xt(
    const float* __restrict__ x, unsigned short* __restrict__ Xt) {
  __shared__ float T[32][33];
  const int gid = blockIdx.x;
  const int b  = gid / (32 * 12);
  const int r  = gid % (32 * 12);
  const int jt = r / 12, ct = r % 12;
  const int j0 = jt * 32, c0 = ct * 32;
  const int tx = threadIdx.x & 31, ty = threadIdx.x >> 5;   // ty 0..7
#pragma unroll
  for (int k = 0; k < 4; ++k)
    T[ty + 8 * k][tx] = x[(size_t)(b * S_ + j0 + ty + 8 * k) * D_ + c0 + tx];
  __syncthreads();
#pragma unroll
  for (int k = 0; k < 4; ++k) {
    int c = ty + 8 * k;
    Xt[((size_t)b * D_ + c0 + c) * S_ + j0 + tx] = (unsigned short)f2bf(T[tx][c]);
  }
}

// ---------------------------------------------------------------------------
// K-FUSED: logits + bias + softmax + P-write + PV, one kernel. Deletes the
// 64 MB attn re-read that k_out did. Block = (b, 32 i-rows), 256 thr.
// Wave (is, h) = (i-sub 16 rows, half-role). Phase 1: online (m,l) over the
// wave's 8 j-tiles (K direct from L2-resident Kb), LDS combine across h.
// Phase 2, per 64-j tile: recompute QK^T quarter -> normalized P written
// once to attn AND staged bf16 in Ps LDS; PV MFMAs read A from Ps and B
// DIRECT from L2-resident Xt (no X staging). Out kept in 12 f32x4 accs.
// ---------------------------------------------------------------------------
__global__ __launch_bounds__(256) void k_fused(
    const unsigned short* __restrict__ Qb, const unsigned short* __restrict__ Kb,
    const float* __restrict__ bias, const unsigned short* __restrict__ Xt,
    float* __restrict__ attn, float* __restrict__ out) {
  __shared__ float Ms[2][2][16], Ls[2][2][16];
  __shared__ __attribute__((aligned(16))) short Ps[32 * 72];   // [i][j] bf16

  const int gid0 = blockIdx.x;
  const int gid  = (gid0 & 7) * 64 + (gid0 >> 3);   // 512 % 8 == 0, bijective
  const int b  = gid >> 5;
  const int i0 = (gid & 31) * 32;
  const int tid = threadIdx.x, lane = tid & 63, w = tid >> 6;
  const int is = w >> 1, h = w & 1;
  const int col = lane & 15, quad = lane >> 4;
  const int ib = i0 + is * 16;          // wave's i-sub base
  const int iq = ib + quad * 4;         // lane's acc rows iq..iq+3

  // Q fragment (A rows indexed by col), hoisted for both K-steps
  const unsigned short* qp = &Qb[(size_t)(b * S_ + ib + col) * QK_];
  const bf16x8 qf0 = *(const bf16x8*)&qp[quad * 8];
  const bf16x8 qf1 = *(const bf16x8*)&qp[32 + quad * 8];

  float m[4] = {-3.0e38f, -3.0e38f, -3.0e38f, -3.0e38f};
  float l[4] = {0.f, 0.f, 0.f, 0.f};

  // ---- phase 1: online (m,l) over this wave's 8 j-tiles ----
#pragma unroll
  for (int st = 0; st < 8; ++st) {
    const int j0 = (h * 8 + st) * 64;
    const unsigned short* kp = &Kb[(size_t)(b * S_ + j0 + col) * QK_];
    f32x4 acc[4] = {{0.f,0.f,0.f,0.f},{0.f,0.f,0.f,0.f},
                    {0.f,0.f,0.f,0.f},{0.f,0.f,0.f,0.f}};
#pragma unroll
    for (int s = 0; s < 4; ++s) {
      bf16x8 k0 = *(const bf16x8*)&kp[(s * 16) * QK_ + quad * 8];
      bf16x8 k1 = *(const bf16x8*)&kp[(s * 16) * QK_ + 32 + quad * 8];
      acc[s] = __builtin_amdgcn_mfma_f32_16x16x32_bf16(qf0, k0, acc[s], 0, 0, 0);
      acc[s] = __builtin_amdgcn_mfma_f32_16x16x32_bf16(qf1, k1, acc[s], 0, 0, 0);
    }
#pragma unroll
    for (int r = 0; r < 4; ++r) {
      float sv0 = acc[0][r] + bias[(size_t)(iq + r) * S_ + j0 + 0 * 16 + col];
      float sv1 = acc[1][r] + bias[(size_t)(iq + r) * S_ + j0 + 1 * 16 + col];
      float sv2 = acc[2][r] + bias[(size_t)(iq + r) * S_ + j0 + 2 * 16 + col];
      float sv3 = acc[3][r] + bias[(size_t)(iq + r) * S_ + j0 + 3 * 16 + col];
      float t = fmaxf(fmaxf(sv0, sv1), fmaxf(sv2, sv3));
#pragma unroll
      for (int off = 8; off >= 1; off >>= 1) t = fmaxf(t, __shfl_xor(t, off));
      const float mn = fmaxf(m[r], t);
      float sum = __expf(sv0 - mn) + __expf(sv1 - mn) +
                  __expf(sv2 - mn) + __expf(sv3 - mn);
#pragma unroll
      for (int off = 8; off >= 1; off >>= 1) sum += __shfl_xor(sum, off);
      l[r] = l[r] * __expf(m[r] - mn) + sum;
      m[r] = mn;
    }
  }

  if (col == 0) {
#pragma unroll
    for (int r = 0; r < 4; ++r) {
      Ms[is][h][quad * 4 + r] = m[r];
      Ls[is][h][quad * 4 + r] = l[r];
    }
  }
  __syncthreads();

  float gm[4], inv[4];
#pragma unroll
  for (int r = 0; r < 4; ++r) {
    const int row = quad * 4 + r;
    const float m0 = Ms[is][0][row], m1 = Ms[is][1][row];
    const float g  = fmaxf(m0, m1);
    const float L  = Ls[is][0][row] * __expf(m0 - g) +
                     Ls[is][1][row] * __expf(m1 - g);
    gm[r]  = g;
    inv[r] = 1.0f / L;
  }

  // ---- phase 2: per j-tile, P-quarter -> attn + Ps; PV accumulate ----
  f32x4 oacc[12] = {{0.f,0.f,0.f,0.f},{0.f,0.f,0.f,0.f},{0.f,0.f,0.f,0.f},
                    {0.f,0.f,0.f,0.f},{0.f,0.f,0.f,0.f},{0.f,0.f,0.f,0.f},
                    {0.f,0.f,0.f,0.f},{0.f,0.f,0.f,0.f},{0.f,0.f,0.f,0.f},
                    {0.f,0.f,0.f,0.f},{0.f,0.f,0.f,0.f},{0.f,0.f,0.f,0.f}};
  const unsigned short* xb = &Xt[((size_t)b * D_ + h * 192) * S_];

  for (int jt = 0; jt < 16; ++jt) {
    const int j0 = jt * 64;
    // recompute this wave's P quarter (rows is*16.., cols h*32..)
    const unsigned short* kp = &Kb[(size_t)(b * S_ + j0 + col) * QK_];
    f32x4 a2[2] = {{0.f,0.f,0.f,0.f},{0.f,0.f,0.f,0.f}};
#pragma unroll
    for (int ss = 0; ss < 2; ++ss) {
      const int s = 2 * h + ss;
      bf16x8 k0 = *(const bf16x8*)&kp[(s * 16) * QK_ + quad * 8];
      bf16x8 k1 = *(const bf16x8*)&kp[(s * 16) * QK_ + 32 + quad * 8];
      a2[ss] = __builtin_amdgcn_mfma_f32_16x16x32_bf16(qf0, k0, a2[ss], 0, 0, 0);
      a2[ss] = __builtin_amdgcn_mfma_f32_16x16x32_bf16(qf1, k1, a2[ss], 0, 0, 0);
    }
    __syncthreads();   // previous tile's PV reads of Ps are done
#pragma unroll
    for (int ss = 0; ss < 2; ++ss) {
      const int s = 2 * h + ss;
#pragma unroll
      for (int r = 0; r < 4; ++r) {
        const float sv = a2[ss][r] +
            bias[(size_t)(iq + r) * S_ + j0 + s * 16 + col];
        const float p = __expf(sv - gm[r]) * inv[r];
        attn[(size_t)(b * S_ + iq + r) * S_ + j0 + s * 16 + col] = p;
        Ps[(is * 16 + quad * 4 + r) * 72 + s * 16 + col] = f2bf(p);
      }
    }
    __syncthreads();   // Ps tile complete (both h-waves)
#pragma unroll
    for (int ks = 0; ks < 2; ++ks) {
      bf16x8 aF = *(const bf16x8*)&Ps[(is * 16 + col) * 72 + ks * 32 + quad * 8];
#pragma unroll
      for (int cs = 0; cs < 12; ++cs) {
        bf16x8 bF = *(const bf16x8*)
            &xb[(size_t)(cs * 16 + col) * S_ + j0 + ks * 32 + quad * 8];
        oacc[cs] = __builtin_amdgcn_mfma_f32_16x16x32_bf16(aF, bF, oacc[cs], 0, 0, 0);
      }
    }
  }

#pragma unroll
  for (int cs = 0; cs < 12; ++cs) {
    const int c = h * 192 + cs * 16 + col;
#pragma unroll
    for (int r = 0; r < 4; ++r) {
      out[(size_t)(b * S_ + iq + r) * D_ + c] = oacc[cs][r];
    }
  }
}

extern "C" void kernel_launch(void* const* d_in, const int* in_sizes, int n_in,
                              void* d_out, int out_size, void* d_ws, size_t ws_size,
                              hipStream_t stream) {
  const float* x  = (const float*)d_in[0];
  const float* qw = (const float*)d_in[1];
  const float* qb = (const float*)d_in[2];
  const float* kw = (const float*)d_in[3];
  const float* ab = (const float*)d_in[4];

  float* out  = (float*)d_out;
  float* attn = out + (size_t)B_ * S_ * D_;          // outputs concatenated

  unsigned short* Qb = (unsigned short*)d_ws;        // bf16 Q [B][S][64]
  unsigned short* Kb = Qb + (size_t)B_ * S_ * QK_;   // bf16 K [B][S][64]
  unsigned short* Xt = Kb + (size_t)B_ * S_ * QK_;   // bf16 X^T [B][384][1024]

  k_proj  <<<2 * S_,       256, 0, stream>>>(x, qw, qb, kw, Qb, Kb);
  k_xt    <<<B_ * 32 * 12, 256, 0, stream>>>(x, Xt);
  k_fused <<<B_ * 32,      256, 0, stream>>>(Qb, Kb, ab, Xt, attn, out);
}